// Round 2
// baseline (596.552 us; speedup 1.0000x reference)
//
#include <hip/hip_runtime.h>
#include <stdint.h>

#define NP 8192           // particles
#define NC 8192           // channels

__host__ __device__ inline uint32_t rotl32(uint32_t x, int r) {
  return (x << r) | (x >> (32 - r));
}

// JAX threefry2x32: 20 rounds, key schedule injection every 4 rounds.
__host__ __device__ inline void threefry2x32(uint32_t k0, uint32_t k1,
                                             uint32_t x0, uint32_t x1,
                                             uint32_t& o0, uint32_t& o1) {
  uint32_t ks2 = k0 ^ k1 ^ 0x1BD11BDAu;
  x0 += k0; x1 += k1;
#define TF_R(r) { x0 += x1; x1 = rotl32(x1, (r)); x1 ^= x0; }
  TF_R(13) TF_R(15) TF_R(26) TF_R(6)   x0 += k1;  x1 += ks2 + 1u;
  TF_R(17) TF_R(29) TF_R(16) TF_R(24)  x0 += ks2; x1 += k0 + 2u;
  TF_R(13) TF_R(15) TF_R(26) TF_R(6)   x0 += k0;  x1 += k1 + 3u;
  TF_R(17) TF_R(29) TF_R(16) TF_R(24)  x0 += k1;  x1 += ks2 + 4u;
  TF_R(13) TF_R(15) TF_R(26) TF_R(6)   x0 += ks2; x1 += k0 + 5u;
#undef TF_R
  o0 = x0; o1 = x1;
}

// partitionable threefry random_bits, 32-bit: counter=(0,i), bits = o0 ^ o1
__device__ inline uint32_t tf_bits(uint32_t k0, uint32_t k1, uint32_t i) {
  uint32_t o0, o1;
  threefry2x32(k0, k1, 0u, i, o0, o1);
  return o0 ^ o1;
}

// uniform [0,1): (bits>>9)|0x3f800000 -> [1,2) -> -1
__device__ inline float u01(uint32_t bits) {
  return __uint_as_float((bits >> 9) | 0x3f800000u) - 1.0f;
}

// XLA ErfInv32 (Giles) polynomial
__device__ inline float erfinvf_(float x) {
  float w = -log1pf(-x * x);
  float p;
  if (w < 5.0f) {
    w -= 2.5f;
    p = 2.81022636e-08f;
    p = fmaf(p, w, 3.43273939e-07f);
    p = fmaf(p, w, -3.5233877e-06f);
    p = fmaf(p, w, -4.39150654e-06f);
    p = fmaf(p, w, 0.00021858087f);
    p = fmaf(p, w, -0.00125372503f);
    p = fmaf(p, w, -0.00417768164f);
    p = fmaf(p, w, 0.246640727f);
    p = fmaf(p, w, 1.50140941f);
  } else {
    w = sqrtf(w) - 3.0f;
    p = -0.000200214257f;
    p = fmaf(p, w, 0.000100950558f);
    p = fmaf(p, w, 0.00134934322f);
    p = fmaf(p, w, -0.00367342844f);
    p = fmaf(p, w, 0.00573950773f);
    p = fmaf(p, w, -0.0076224613f);
    p = fmaf(p, w, 0.00943887047f);
    p = fmaf(p, w, 1.00167406f);
    p = fmaf(p, w, 2.83297682f);
  }
  return p * x;
}

// z = jax.random.normal(k_noise, (NP,3)) flat; element i from counter (0,i)
__global__ void __launch_bounds__(256) k_normal(uint32_t k0, uint32_t k1, float* __restrict__ z) {
  uint32_t j = blockIdx.x * blockDim.x + threadIdx.x;
  if (j >= NP * 3) return;
  uint32_t bits = tf_bits(k0, k1, j);
  const float lo = -0.99999994f;        // nextafter(-1,0)
  float v = fmaxf(lo, u01(bits) * 2.0f + lo);  // span fp32(1-lo) == 2.0
  z[j] = 1.41421356f * erfinvf_(v);            // fp32(sqrt(2))
}

// state = sv @ T^T + z @ chol(Q)
__global__ void __launch_bounds__(256) k_state(const float* __restrict__ sv,
                                               const float* __restrict__ T,
                                               const float* __restrict__ Q,
                                               const float* __restrict__ z,
                                               float* __restrict__ st) {
  int i = blockIdx.x * blockDim.x + threadIdx.x;
  if (i >= NP) return;
  float L00 = sqrtf(Q[0]);
  float L10 = Q[3] / L00, L20 = Q[6] / L00;
  float L11 = sqrtf(Q[4] - L10 * L10);
  float L21 = (Q[7] - L20 * L10) / L11;
  float L22 = sqrtf(Q[8] - L20 * L20 - L21 * L21);
  float s0 = sv[i * 3], s1 = sv[i * 3 + 1], s2 = sv[i * 3 + 2];
  float z0 = z[i * 3], z1 = z[i * 3 + 1], z2 = z[i * 3 + 2];
  float u0 = s0 * T[0] + s1 * T[1] + s2 * T[2];
  float u1 = s0 * T[3] + s1 * T[4] + s2 * T[5];
  float u2 = s0 * T[6] + s1 * T[7] + s2 * T[8];
  st[i * 3]     = u0 + (z0 * L00 + z1 * L10 + z2 * L20);
  st[i * 3 + 1] = u1 + (z1 * L11 + z2 * L21);
  st[i * 3 + 2] = u2 + (z2 * L22);
}

// logits[i] = log( sum_j (in[i*NC+j] - H[j]·state[i])^2 )
__global__ void __launch_bounds__(256) k_weights(const float* __restrict__ in,
                                                 const float* __restrict__ H,
                                                 const float* __restrict__ st,
                                                 float* __restrict__ logits) {
  int i = blockIdx.x;
  float s0 = st[i * 3], s1 = st[i * 3 + 1], s2 = st[i * 3 + 2];
  const float4* inrow = (const float4*)(in + (size_t)i * NC);
  const float4* H4 = (const float4*)H;
  float acc = 0.0f;
  for (int it = threadIdx.x; it < NC / 4; it += 256) {
    float4 x = inrow[it];
    float4 h0 = H4[it * 3 + 0];
    float4 h1 = H4[it * 3 + 1];
    float4 h2 = H4[it * 3 + 2];
    float p0 = h0.x * s0 + h0.y * s1 + h0.z * s2;
    float p1 = h0.w * s0 + h1.x * s1 + h1.y * s2;
    float p2 = h1.z * s0 + h1.w * s1 + h2.x * s2;
    float p3 = h2.y * s0 + h2.z * s1 + h2.w * s2;
    float d0 = x.x - p0, d1 = x.y - p1, d2 = x.z - p2, d3 = x.w - p3;
    acc += d0 * d0 + d1 * d1 + d2 * d2 + d3 * d3;
  }
  __shared__ float red[256];
  red[threadIdx.x] = acc;
  __syncthreads();
  for (int s = 128; s > 0; s >>= 1) {
    if (threadIdx.x < s) red[threadIdx.x] += red[threadIdx.x + s];
    __syncthreads();
  }
  if (threadIdx.x == 0) logits[i] = logf(red[0]);
}

// idx[s] = argmax_i( gumbel[s,i] + logits[i] ), gumbel bits from flat counter s*NP+i
__global__ void __launch_bounds__(256) k_resample(uint32_t k0, uint32_t k1,
                                                  const float* __restrict__ logits,
                                                  int* __restrict__ idx) {
  __shared__ float lg[NP];  // 32 KB
  for (int t = threadIdx.x; t < NP; t += 256) lg[t] = logits[t];
  __syncthreads();
  uint32_t s = blockIdx.x;
  uint32_t base = s * (uint32_t)NP;
  const float TINY = 1.17549435e-38f;
  float b = -3.4e38f;
  int bi = 0;
  for (uint32_t i = threadIdx.x; i < NP; i += 256) {
    uint32_t bits = tf_bits(k0, k1, base + i);
    float v = fmaxf(TINY, u01(bits) * 1.0f + TINY);  // span fp32(1-tiny) == 1.0
    float g = -logf(-logf(v)) + lg[i];
    if (g > b) { b = g; bi = (int)i; }  // strict >: first max wins (i ascending per thread)
  }
  __shared__ float rv[256];
  __shared__ int ri[256];
  rv[threadIdx.x] = b;
  ri[threadIdx.x] = bi;
  __syncthreads();
  for (int st = 128; st > 0; st >>= 1) {
    if (threadIdx.x < st) {
      float va = rv[threadIdx.x], vb = rv[threadIdx.x + st];
      int ia = ri[threadIdx.x], ib = ri[threadIdx.x + st];
      if (vb > va || (vb == va && ib < ia)) { rv[threadIdx.x] = vb; ri[threadIdx.x] = ib; }
    }
    __syncthreads();
  }
  if (threadIdx.x == 0) idx[s] = ri[0];
}

// out = mean over s of state[idx[s]]
__global__ void __launch_bounds__(256) k_mean(const float* __restrict__ st,
                                              const int* __restrict__ idx,
                                              float* __restrict__ out) {
  double a0 = 0, a1 = 0, a2 = 0;
  for (int s = threadIdx.x; s < NP; s += 256) {
    int j = idx[s];
    a0 += st[j * 3];
    a1 += st[j * 3 + 1];
    a2 += st[j * 3 + 2];
  }
  __shared__ double r0[256], r1[256], r2[256];
  r0[threadIdx.x] = a0; r1[threadIdx.x] = a1; r2[threadIdx.x] = a2;
  __syncthreads();
  for (int s = 128; s > 0; s >>= 1) {
    if (threadIdx.x < s) {
      r0[threadIdx.x] += r0[threadIdx.x + s];
      r1[threadIdx.x] += r1[threadIdx.x + s];
      r2[threadIdx.x] += r2[threadIdx.x + s];
    }
    __syncthreads();
  }
  if (threadIdx.x == 0) {
    out[0] = (float)(r0[0] / NP);
    out[1] = (float)(r1[0] / NP);
    out[2] = (float)(r2[0] / NP);
  }
}

extern "C" void kernel_launch(void* const* d_in, const int* in_sizes, int n_in,
                              void* d_out, int out_size, void* d_ws, size_t ws_size,
                              hipStream_t stream) {
  const float* in = (const float*)d_in[0];   // (1, C, P)
  const float* sv = (const float*)d_in[1];   // (P, 3)
  const float* T  = (const float*)d_in[2];   // (3, 3)
  const float* Q  = (const float*)d_in[3];   // (3, 3)
  const float* H  = (const float*)d_in[4];   // (C, 3)
  float* out = (float*)d_out;                // (3,)

  // ws layout
  float* z      = (float*)d_ws;          // 24576 f
  float* st     = z + 24576;             // 24576 f
  float* logits = st + 24576;            // 8192 f
  int*   idx    = (int*)(logits + NP);   // 8192 i

  // partitionable split(key(42)): key data (0,42); subkey j = threefry(key, (0, j)) both outputs
  uint32_t nk0, nk1, ck0, ck1;
  threefry2x32(0u, 42u, 0u, 0u, nk0, nk1);  // k_noise
  threefry2x32(0u, 42u, 0u, 1u, ck0, ck1);  // k_cat

  hipLaunchKernelGGL(k_normal, dim3(96), dim3(256), 0, stream, nk0, nk1, z);
  hipLaunchKernelGGL(k_state, dim3(32), dim3(256), 0, stream, sv, T, Q, z, st);
  hipLaunchKernelGGL(k_weights, dim3(NP), dim3(256), 0, stream, in, H, st, logits);
  hipLaunchKernelGGL(k_resample, dim3(NP), dim3(256), 0, stream, ck0, ck1, logits, idx);
  hipLaunchKernelGGL(k_mean, dim3(1), dim3(256), 0, stream, st, idx, out);
}

// Round 3
// 576.093 us; speedup vs baseline: 1.0355x; 1.0355x over previous
//
#include <hip/hip_runtime.h>
#include <stdint.h>

#define NP 8192           // particles
#define NC 8192           // channels

__host__ __device__ inline uint32_t rotl32(uint32_t x, int r) {
  return (x << r) | (x >> (32 - r));
}

// JAX threefry2x32: 20 rounds, key schedule injection every 4 rounds.
__host__ __device__ inline void threefry2x32(uint32_t k0, uint32_t k1,
                                             uint32_t x0, uint32_t x1,
                                             uint32_t& o0, uint32_t& o1) {
  uint32_t ks2 = k0 ^ k1 ^ 0x1BD11BDAu;
  x0 += k0; x1 += k1;
#define TF_R(r) { x0 += x1; x1 = rotl32(x1, (r)); x1 ^= x0; }
  TF_R(13) TF_R(15) TF_R(26) TF_R(6)   x0 += k1;  x1 += ks2 + 1u;
  TF_R(17) TF_R(29) TF_R(16) TF_R(24)  x0 += ks2; x1 += k0 + 2u;
  TF_R(13) TF_R(15) TF_R(26) TF_R(6)   x0 += k0;  x1 += k1 + 3u;
  TF_R(17) TF_R(29) TF_R(16) TF_R(24)  x0 += k1;  x1 += ks2 + 4u;
  TF_R(13) TF_R(15) TF_R(26) TF_R(6)   x0 += ks2; x1 += k0 + 5u;
#undef TF_R
  o0 = x0; o1 = x1;
}

// partitionable threefry random_bits, 32-bit: counter=(0,i), bits = o0 ^ o1
__device__ inline uint32_t tf_bits(uint32_t k0, uint32_t k1, uint32_t i) {
  uint32_t o0, o1;
  threefry2x32(k0, k1, 0u, i, o0, o1);
  return o0 ^ o1;
}

// uniform [0,1): (bits>>9)|0x3f800000 -> [1,2) -> -1
__device__ inline float u01(uint32_t bits) {
  return __uint_as_float((bits >> 9) | 0x3f800000u) - 1.0f;
}

// XLA ErfInv32 (Giles) polynomial
__device__ inline float erfinvf_(float x) {
  float w = -log1pf(-x * x);
  float p;
  if (w < 5.0f) {
    w -= 2.5f;
    p = 2.81022636e-08f;
    p = fmaf(p, w, 3.43273939e-07f);
    p = fmaf(p, w, -3.5233877e-06f);
    p = fmaf(p, w, -4.39150654e-06f);
    p = fmaf(p, w, 0.00021858087f);
    p = fmaf(p, w, -0.00125372503f);
    p = fmaf(p, w, -0.00417768164f);
    p = fmaf(p, w, 0.246640727f);
    p = fmaf(p, w, 1.50140941f);
  } else {
    w = sqrtf(w) - 3.0f;
    p = -0.000200214257f;
    p = fmaf(p, w, 0.000100950558f);
    p = fmaf(p, w, 0.00134934322f);
    p = fmaf(p, w, -0.00367342844f);
    p = fmaf(p, w, 0.00573950773f);
    p = fmaf(p, w, -0.0076224613f);
    p = fmaf(p, w, 0.00943887047f);
    p = fmaf(p, w, 1.00167406f);
    p = fmaf(p, w, 2.83297682f);
  }
  return p * x;
}

// z = jax.random.normal(k_noise, (NP,3)) flat; element i from counter (0,i)
__global__ void __launch_bounds__(256) k_normal(uint32_t k0, uint32_t k1, float* __restrict__ z) {
  uint32_t j = blockIdx.x * blockDim.x + threadIdx.x;
  if (j >= NP * 3) return;
  uint32_t bits = tf_bits(k0, k1, j);
  const float lo = -0.99999994f;        // nextafter(-1,0)
  float v = fmaxf(lo, u01(bits) * 2.0f + lo);  // span fp32(1-lo) == 2.0
  z[j] = 1.41421356f * erfinvf_(v);            // fp32(sqrt(2))
}

// state = sv @ T^T + z @ chol(Q)
__global__ void __launch_bounds__(256) k_state(const float* __restrict__ sv,
                                               const float* __restrict__ T,
                                               const float* __restrict__ Q,
                                               const float* __restrict__ z,
                                               float* __restrict__ st) {
  int i = blockIdx.x * blockDim.x + threadIdx.x;
  if (i >= NP) return;
  float L00 = sqrtf(Q[0]);
  float L10 = Q[3] / L00, L20 = Q[6] / L00;
  float L11 = sqrtf(Q[4] - L10 * L10);
  float L21 = (Q[7] - L20 * L10) / L11;
  float L22 = sqrtf(Q[8] - L20 * L20 - L21 * L21);
  float s0 = sv[i * 3], s1 = sv[i * 3 + 1], s2 = sv[i * 3 + 2];
  float z0 = z[i * 3], z1 = z[i * 3 + 1], z2 = z[i * 3 + 2];
  float u0 = s0 * T[0] + s1 * T[1] + s2 * T[2];
  float u1 = s0 * T[3] + s1 * T[4] + s2 * T[5];
  float u2 = s0 * T[6] + s1 * T[7] + s2 * T[8];
  st[i * 3]     = u0 + (z0 * L00 + z1 * L10 + z2 * L20);
  st[i * 3 + 1] = u1 + (z1 * L11 + z2 * L21);
  st[i * 3 + 2] = u2 + (z2 * L22);
}

// winv[i] = 1 / sum_j (in[i*NC+j] - H[j]·state[i])^2   — one wave per row
__global__ void __launch_bounds__(256) k_weights(const float* __restrict__ in,
                                                 const float* __restrict__ H,
                                                 const float* __restrict__ st,
                                                 float* __restrict__ winv) {
  int wave = threadIdx.x >> 6;
  int lane = threadIdx.x & 63;
  int row = blockIdx.x * 4 + wave;
  float s0 = st[row * 3], s1 = st[row * 3 + 1], s2 = st[row * 3 + 2];
  const float4* inrow = (const float4*)(in + (size_t)row * NC);
  const float4* H4 = (const float4*)H;
  float acc = 0.0f;
#pragma unroll 8
  for (int it = lane; it < NC / 4; it += 64) {
    float4 x = inrow[it];
    float4 h0 = H4[it * 3 + 0];
    float4 h1 = H4[it * 3 + 1];
    float4 h2 = H4[it * 3 + 2];
    float p0 = h0.x * s0 + h0.y * s1 + h0.z * s2;
    float p1 = h0.w * s0 + h1.x * s1 + h1.y * s2;
    float p2 = h1.z * s0 + h1.w * s1 + h2.x * s2;
    float p3 = h2.y * s0 + h2.z * s1 + h2.w * s2;
    float d0 = x.x - p0, d1 = x.y - p1, d2 = x.z - p2, d3 = x.w - p3;
    acc += d0 * d0 + d1 * d1 + d2 * d2 + d3 * d3;
  }
#pragma unroll
  for (int off = 32; off > 0; off >>= 1) acc += __shfl_down(acc, off, 64);
  if (lane == 0) winv[row] = 1.0f / acc;
}

// Exponential race: idx[s] = argmin_i( -log(v_{s,i}) / w_i )
//   == argmax_i( gumbel_{s,i} + log(w_i) )  (monotone transform; ulp-level ties only)
__global__ void __launch_bounds__(256) k_resample(uint32_t k0, uint32_t k1,
                                                  const float* __restrict__ winv,
                                                  int* __restrict__ idx) {
  __shared__ float wi[NP];  // 32 KB
  for (int t = threadIdx.x; t < NP; t += 256) wi[t] = winv[t];
  __syncthreads();
  uint32_t s = blockIdx.x;
  uint32_t base = s * (uint32_t)NP;
  const float TINY = 1.17549435e-38f;
  float best = 3.4e38f;
  int bi = 0;
#pragma unroll 4
  for (uint32_t i = threadIdx.x; i < NP; i += 256) {
    uint32_t bits = tf_bits(k0, k1, base + i);
    float v = fmaxf(TINY, u01(bits) + TINY);  // JAX uniform(tiny,1): span fp32(1-tiny)==1.0
    float y = -__logf(v);                     // native v_log_f32 * ln2
    float r = y * wi[i];
    if (r < best) { best = r; bi = (int)i; }  // strict <: first (lowest i) wins per thread
  }
  __shared__ float rv[256];
  __shared__ int ri[256];
  rv[threadIdx.x] = best;
  ri[threadIdx.x] = bi;
  __syncthreads();
  for (int stp = 128; stp > 0; stp >>= 1) {
    if (threadIdx.x < stp) {
      float va = rv[threadIdx.x], vb = rv[threadIdx.x + stp];
      int ia = ri[threadIdx.x], ib = ri[threadIdx.x + stp];
      if (vb < va || (vb == va && ib < ia)) { rv[threadIdx.x] = vb; ri[threadIdx.x] = ib; }
    }
    __syncthreads();
  }
  if (threadIdx.x == 0) idx[s] = ri[0];
}

// out = mean over s of state[idx[s]]
__global__ void __launch_bounds__(256) k_mean(const float* __restrict__ st,
                                              const int* __restrict__ idx,
                                              float* __restrict__ out) {
  double a0 = 0, a1 = 0, a2 = 0;
  for (int s = threadIdx.x; s < NP; s += 256) {
    int j = idx[s];
    a0 += st[j * 3];
    a1 += st[j * 3 + 1];
    a2 += st[j * 3 + 2];
  }
  __shared__ double r0[256], r1[256], r2[256];
  r0[threadIdx.x] = a0; r1[threadIdx.x] = a1; r2[threadIdx.x] = a2;
  __syncthreads();
  for (int s = 128; s > 0; s >>= 1) {
    if (threadIdx.x < s) {
      r0[threadIdx.x] += r0[threadIdx.x + s];
      r1[threadIdx.x] += r1[threadIdx.x + s];
      r2[threadIdx.x] += r2[threadIdx.x + s];
    }
    __syncthreads();
  }
  if (threadIdx.x == 0) {
    out[0] = (float)(r0[0] / NP);
    out[1] = (float)(r1[0] / NP);
    out[2] = (float)(r2[0] / NP);
  }
}

extern "C" void kernel_launch(void* const* d_in, const int* in_sizes, int n_in,
                              void* d_out, int out_size, void* d_ws, size_t ws_size,
                              hipStream_t stream) {
  const float* in = (const float*)d_in[0];   // (1, C, P)
  const float* sv = (const float*)d_in[1];   // (P, 3)
  const float* T  = (const float*)d_in[2];   // (3, 3)
  const float* Q  = (const float*)d_in[3];   // (3, 3)
  const float* H  = (const float*)d_in[4];   // (C, 3)
  float* out = (float*)d_out;                // (3,)

  // ws layout
  float* z    = (float*)d_ws;          // 24576 f
  float* st   = z + 24576;             // 24576 f
  float* winv = st + 24576;            // 8192 f
  int*   idx  = (int*)(winv + NP);     // 8192 i

  // partitionable split(key(42)): subkey j = threefry(key, (0, j)) both outputs
  uint32_t nk0, nk1, ck0, ck1;
  threefry2x32(0u, 42u, 0u, 0u, nk0, nk1);  // k_noise
  threefry2x32(0u, 42u, 0u, 1u, ck0, ck1);  // k_cat

  hipLaunchKernelGGL(k_normal, dim3(96), dim3(256), 0, stream, nk0, nk1, z);
  hipLaunchKernelGGL(k_state, dim3(32), dim3(256), 0, stream, sv, T, Q, z, st);
  hipLaunchKernelGGL(k_weights, dim3(NP / 4), dim3(256), 0, stream, in, H, st, winv);
  hipLaunchKernelGGL(k_resample, dim3(NP), dim3(256), 0, stream, ck0, ck1, winv, idx);
  hipLaunchKernelGGL(k_mean, dim3(1), dim3(256), 0, stream, st, idx, out);
}

// Round 4
// 563.633 us; speedup vs baseline: 1.0584x; 1.0221x over previous
//
#include <hip/hip_runtime.h>
#include <stdint.h>

#define NP 8192           // particles
#define NC 8192           // channels

__host__ __device__ inline uint32_t rotl32(uint32_t x, int r) {
  return __builtin_rotateleft32(x, (unsigned)r);   // v_alignbit_b32 on gfx950
}

// JAX threefry2x32: 20 rounds, key schedule injection every 4 rounds.
__host__ __device__ inline void threefry2x32(uint32_t k0, uint32_t k1,
                                             uint32_t x0, uint32_t x1,
                                             uint32_t& o0, uint32_t& o1) {
  uint32_t ks2 = k0 ^ k1 ^ 0x1BD11BDAu;
  x0 += k0; x1 += k1;
#define TF_R(r) { x0 += x1; x1 = rotl32(x1, (r)); x1 ^= x0; }
  TF_R(13) TF_R(15) TF_R(26) TF_R(6)   x0 += k1;  x1 += ks2 + 1u;
  TF_R(17) TF_R(29) TF_R(16) TF_R(24)  x0 += ks2; x1 += k0 + 2u;
  TF_R(13) TF_R(15) TF_R(26) TF_R(6)   x0 += k0;  x1 += k1 + 3u;
  TF_R(17) TF_R(29) TF_R(16) TF_R(24)  x0 += k1;  x1 += ks2 + 4u;
  TF_R(13) TF_R(15) TF_R(26) TF_R(6)   x0 += ks2; x1 += k0 + 5u;
#undef TF_R
  o0 = x0; o1 = x1;
}

// partitionable threefry random_bits, 32-bit: counter=(0,i), bits = o0 ^ o1
__device__ inline uint32_t tf_bits(uint32_t k0, uint32_t k1, uint32_t i) {
  uint32_t o0, o1;
  threefry2x32(k0, k1, 0u, i, o0, o1);
  return o0 ^ o1;
}

// uniform [0,1): (bits>>9)|0x3f800000 -> [1,2) -> -1
__device__ inline float u01(uint32_t bits) {
  return __uint_as_float((bits >> 9) | 0x3f800000u) - 1.0f;
}

// XLA ErfInv32 (Giles) polynomial
__device__ inline float erfinvf_(float x) {
  float w = -log1pf(-x * x);
  float p;
  if (w < 5.0f) {
    w -= 2.5f;
    p = 2.81022636e-08f;
    p = fmaf(p, w, 3.43273939e-07f);
    p = fmaf(p, w, -3.5233877e-06f);
    p = fmaf(p, w, -4.39150654e-06f);
    p = fmaf(p, w, 0.00021858087f);
    p = fmaf(p, w, -0.00125372503f);
    p = fmaf(p, w, -0.00417768164f);
    p = fmaf(p, w, 0.246640727f);
    p = fmaf(p, w, 1.50140941f);
  } else {
    w = sqrtf(w) - 3.0f;
    p = -0.000200214257f;
    p = fmaf(p, w, 0.000100950558f);
    p = fmaf(p, w, 0.00134934322f);
    p = fmaf(p, w, -0.00367342844f);
    p = fmaf(p, w, 0.00573950773f);
    p = fmaf(p, w, -0.0076224613f);
    p = fmaf(p, w, 0.00943887047f);
    p = fmaf(p, w, 1.00167406f);
    p = fmaf(p, w, 2.83297682f);
  }
  return p * x;
}

// Fused: blocks 0..31 -> state = sv@T^T + z@chol(Q) (z regenerated per thread);
//        blocks 32..127 -> Ht (column-major transpose of H, 3 x 8192)
__global__ void __launch_bounds__(256) k_prep(uint32_t k0, uint32_t k1,
                                              const float* __restrict__ sv,
                                              const float* __restrict__ T,
                                              const float* __restrict__ Q,
                                              const float* __restrict__ H,
                                              float* __restrict__ st,
                                              float* __restrict__ ht) {
  int b = blockIdx.x;
  if (b < 32) {
    int i = b * 256 + threadIdx.x;  // particle
    const float lo = -0.99999994f;  // nextafter(-1,0)
    float zz[3];
#pragma unroll
    for (int k = 0; k < 3; k++) {
      uint32_t bits = tf_bits(k0, k1, 3u * (uint32_t)i + (uint32_t)k);
      float v = fmaxf(lo, u01(bits) * 2.0f + lo);  // span fp32(1-lo) == 2.0
      zz[k] = 1.41421356f * erfinvf_(v);           // fp32(sqrt(2))
    }
    float L00 = sqrtf(Q[0]);
    float L10 = Q[3] / L00, L20 = Q[6] / L00;
    float L11 = sqrtf(Q[4] - L10 * L10);
    float L21 = (Q[7] - L20 * L10) / L11;
    float L22 = sqrtf(Q[8] - L20 * L20 - L21 * L21);
    float s0 = sv[i * 3], s1 = sv[i * 3 + 1], s2 = sv[i * 3 + 2];
    float u0 = s0 * T[0] + s1 * T[1] + s2 * T[2];
    float u1 = s0 * T[3] + s1 * T[4] + s2 * T[5];
    float u2 = s0 * T[6] + s1 * T[7] + s2 * T[8];
    st[i * 3]     = u0 + (zz[0] * L00 + zz[1] * L10 + zz[2] * L20);
    st[i * 3 + 1] = u1 + (zz[1] * L11 + zz[2] * L21);
    st[i * 3 + 2] = u2 + (zz[2] * L22);
  } else {
    int t = (b - 32) * 256 + threadIdx.x;  // 0..24575
    int k = t >> 13, j = t & (NP - 1);
    ht[t] = H[j * 3 + k];  // ht[k*8192 + j] = H[j][k]
  }
}

// winv[i] = 1 / sum_j (in[i*NC+j] - Ht[.][j]·state[i])^2   — one wave per row,
// all four streams coalesced float4.
__global__ void __launch_bounds__(256) k_weights(const float* __restrict__ in,
                                                 const float* __restrict__ ht,
                                                 const float* __restrict__ st,
                                                 float* __restrict__ winv) {
  int wave = threadIdx.x >> 6;
  int lane = threadIdx.x & 63;
  int row = blockIdx.x * 4 + wave;
  float s0 = st[row * 3], s1 = st[row * 3 + 1], s2 = st[row * 3 + 2];
  const float4* inrow = (const float4*)(in + (size_t)row * NC);
  const float4* h0 = (const float4*)ht;
  const float4* h1 = (const float4*)(ht + NC);
  const float4* h2 = (const float4*)(ht + 2 * NC);
  float acc = 0.0f;
#pragma unroll 4
  for (int it = lane; it < NC / 4; it += 64) {
    float4 x = inrow[it];
    float4 a = h0[it];
    float4 b = h1[it];
    float4 c = h2[it];
    float d0 = x.x - (a.x * s0 + b.x * s1 + c.x * s2);
    float d1 = x.y - (a.y * s0 + b.y * s1 + c.y * s2);
    float d2 = x.z - (a.z * s0 + b.z * s1 + c.z * s2);
    float d3 = x.w - (a.w * s0 + b.w * s1 + c.w * s2);
    acc += d0 * d0 + d1 * d1 + d2 * d2 + d3 * d3;
  }
#pragma unroll
  for (int off = 32; off > 0; off >>= 1) acc += __shfl_down(acc, off, 64);
  if (lane == 0) winv[row] = 1.0f / acc;
}

// Exponential race: idx[s] = argmin_i( -log(v_{s,i}) * winv[i] )
//   == argmax_i( gumbel_{s,i} + log(w_i) ). winv (32 KB) stays L1-resident.
__global__ void __launch_bounds__(256) k_resample(uint32_t k0, uint32_t k1,
                                                  const float* __restrict__ winv,
                                                  int* __restrict__ idx) {
  uint32_t s = blockIdx.x;
  uint32_t base = s * (uint32_t)NP;
  const float TINY = 1.17549435e-38f;
  float best = 3.4e38f;
  int bi = 0;
#pragma unroll 4
  for (uint32_t i = threadIdx.x; i < NP; i += 256) {
    uint32_t bits = tf_bits(k0, k1, base + i);
    // JAX uniform(tiny,1): tiny + u*fp32(1-tiny) = tiny + u; == fmax(u, tiny) exactly
    float v = fmaxf(u01(bits), TINY);
    float r = -__logf(v) * winv[i];  // native v_log_f32
    if (r < best) { best = r; bi = (int)i; }  // strict <: first (lowest i) wins per thread
  }
  __shared__ float rv[256];
  __shared__ int ri[256];
  rv[threadIdx.x] = best;
  ri[threadIdx.x] = bi;
  __syncthreads();
  for (int stp = 128; stp > 0; stp >>= 1) {
    if (threadIdx.x < stp) {
      float va = rv[threadIdx.x], vb = rv[threadIdx.x + stp];
      int ia = ri[threadIdx.x], ib = ri[threadIdx.x + stp];
      if (vb < va || (vb == va && ib < ia)) { rv[threadIdx.x] = vb; ri[threadIdx.x] = ib; }
    }
    __syncthreads();
  }
  if (threadIdx.x == 0) idx[s] = ri[0];
}

// out = mean over s of state[idx[s]]
__global__ void __launch_bounds__(1024) k_mean(const float* __restrict__ st,
                                               const int* __restrict__ idx,
                                               float* __restrict__ out) {
  double a0 = 0, a1 = 0, a2 = 0;
  for (int s = threadIdx.x; s < NP; s += 1024) {
    int j = idx[s];
    a0 += st[j * 3];
    a1 += st[j * 3 + 1];
    a2 += st[j * 3 + 2];
  }
  __shared__ double r0[1024], r1[1024], r2[1024];
  r0[threadIdx.x] = a0; r1[threadIdx.x] = a1; r2[threadIdx.x] = a2;
  __syncthreads();
  for (int s = 512; s > 0; s >>= 1) {
    if (threadIdx.x < s) {
      r0[threadIdx.x] += r0[threadIdx.x + s];
      r1[threadIdx.x] += r1[threadIdx.x + s];
      r2[threadIdx.x] += r2[threadIdx.x + s];
    }
    __syncthreads();
  }
  if (threadIdx.x == 0) {
    out[0] = (float)(r0[0] / NP);
    out[1] = (float)(r1[0] / NP);
    out[2] = (float)(r2[0] / NP);
  }
}

extern "C" void kernel_launch(void* const* d_in, const int* in_sizes, int n_in,
                              void* d_out, int out_size, void* d_ws, size_t ws_size,
                              hipStream_t stream) {
  const float* in = (const float*)d_in[0];   // (1, C, P)
  const float* sv = (const float*)d_in[1];   // (P, 3)
  const float* T  = (const float*)d_in[2];   // (3, 3)
  const float* Q  = (const float*)d_in[3];   // (3, 3)
  const float* H  = (const float*)d_in[4];   // (C, 3)
  float* out = (float*)d_out;                // (3,)

  // ws layout
  float* st   = (float*)d_ws;          // 24576 f
  float* ht   = st + 24576;            // 24576 f (H transposed, 3 x 8192)
  float* winv = ht + 24576;            // 8192 f
  int*   idx  = (int*)(winv + NP);     // 8192 i

  // partitionable split(key(42)): subkey j = threefry(key, (0, j)) both outputs
  uint32_t nk0, nk1, ck0, ck1;
  threefry2x32(0u, 42u, 0u, 0u, nk0, nk1);  // k_noise
  threefry2x32(0u, 42u, 0u, 1u, ck0, ck1);  // k_cat

  hipLaunchKernelGGL(k_prep, dim3(128), dim3(256), 0, stream, nk0, nk1, sv, T, Q, H, st, ht);
  hipLaunchKernelGGL(k_weights, dim3(NP / 4), dim3(256), 0, stream, in, ht, st, winv);
  hipLaunchKernelGGL(k_resample, dim3(NP), dim3(256), 0, stream, ck0, ck1, winv, idx);
  hipLaunchKernelGGL(k_mean, dim3(1), dim3(1024), 0, stream, st, idx, out);
}